// Round 8
// baseline (2421.364 us; speedup 1.0000x reference)
//
#include <hip/hip_runtime.h>
#include <cstdint>
#include <cstddef>

typedef unsigned int u32;
typedef unsigned short u16;
typedef float  f32x4 __attribute__((ext_vector_type(4)));
typedef short  s16x8 __attribute__((ext_vector_type(8)));
typedef unsigned short u16x4 __attribute__((ext_vector_type(4)));

typedef const __attribute__((address_space(1))) u32 gbl_u32;
typedef __attribute__((address_space(3))) u32 lds_u32;

__device__ __forceinline__ u16 f2bf(float f) {          // RNE f32->bf16 (finite inputs)
    u32 u = __builtin_bit_cast(u32, f);
    u = (u + 0x7FFFu + ((u >> 16) & 1u)) >> 16;
    return (u16)u;
}

// ---------------- elementwise f32 -> bf16 convert ----------------
__global__ void k_cvt(const float* __restrict__ s, u16* __restrict__ d, int n4) {
    int i = blockIdx.x * 256 + threadIdx.x;
    if (i >= n4) return;
    float4 v = ((const float4*)s)[i];
    u16x4 o = { f2bf(v.x), f2bf(v.y), f2bf(v.z), f2bf(v.w) };
    *(u16x4*)(d + (size_t)i * 4) = o;
}

// ---------------- transpose + convert: src f32 [R][C] -> dst bf16 [C][R] ----------------
__global__ void k_tcvt(const float* __restrict__ s, u16* __restrict__ d, int R, int C) {
    __shared__ float t[32][33];
    int bx = blockIdx.x, by = blockIdx.y;
    int tx = threadIdx.x, ty = threadIdx.y;
    #pragma unroll
    for (int j = ty; j < 32; j += 8)
        t[j][tx] = s[(size_t)(by * 32 + j) * C + bx * 32 + tx];
    __syncthreads();
    #pragma unroll
    for (int j = ty; j < 32; j += 8)
        d[(size_t)(bx * 32 + j) * R + by * 32 + tx] = f2bf(t[tx][j]);
}

__global__ void k_zero(float* __restrict__ p, int n) {
    int i = blockIdx.x * 256 + threadIdx.x;
    if (i < n) p[i] = 0.f;
}

// final reduce: out = bias + sum over splitk partials   (2097152 f32 = 524288 float4)
__global__ void k_reduce(const float* __restrict__ part, const float* __restrict__ bias,
                         float* __restrict__ out, int splitk) {
    int i = blockIdx.x * 256 + threadIdx.x;          // float4 id
    float4 s = ((const float4*)bias)[i & 127];
    for (int j = 0; j < splitk; ++j) {
        float4 p = ((const float4*)part)[(size_t)j * 524288 + i];
        s.x += p.x; s.y += p.y; s.z += p.z; s.w += p.w;
    }
    ((float4*)out)[i] = s;
}

// ================= 128x128xK bf16 GEMM, B given transposed [N][K] ==================
// m97-structure: 4 waves (2x2), BK=32, SINGLE-buffered 16 KiB LDS, plain
// __syncthreads 2-barrier loop. 8 blocks/CU co-resident (launch_bounds(256,8))
// provide latency hiding via cross-block overlap (m114). XOR swizzle adapted to
// 64B rows: slot ^= (row>>1)&3 -> 2-way max (free). global_load_lds width 16.
// MODE 0: QKV projections (bz=mat)  MODE 1: P=exp(qk^T*scale)+rowsum-atomic
// MODE 2: O=(P v)/rowsum            MODE 3: split-K partials of Oattn@Wo
template<int MODE>
__global__ __launch_bounds__(256, 8) void k_gemm(
    const u16* __restrict__ Abase, const u16* __restrict__ Bbase,
    u16* __restrict__ out0, u16* __restrict__ out1, u16* __restrict__ out2,
    float* __restrict__ outf,
    const float* __restrict__ bias0, const float* __restrict__ bias1,
    const float* __restrict__ bias2,
    float* __restrict__ rsum, int bh_base, int ktiles)
{
    constexpr int LDA = (MODE == 2) ? 2048 : (MODE == 3) ? 4096 : 512;
    constexpr int LDB = (MODE == 2) ? 2048 : (MODE == 3) ? 4096 : 512;

    __shared__ u16 lsA[128][32];       // 8 KiB
    __shared__ u16 lsB[128][32];       // 8 KiB

    const int tid = threadIdx.x;
    const int bx = blockIdx.x, by = blockIdx.y, bz = blockIdx.z;

    const u16* A; const u16* Bt;
    if constexpr (MODE == 0) {
        A  = Abase + (size_t)bz * 2097152 + (size_t)by * 128 * 512;
        Bt = Bbase + (size_t)bz * 2097152 + (size_t)bx * 128 * 512;
    } else if constexpr (MODE == 1) {
        int bh = bh_base + bz;
        A  = Abase + (size_t)bh * 1048576 + (size_t)by * 128 * 512;
        Bt = Bbase + (size_t)bh * 1048576 + (size_t)bx * 128 * 512;
    } else if constexpr (MODE == 2) {
        int bh = bh_base + bz;
        A  = Abase + (size_t)bz * 4194304 + (size_t)by * 128 * 2048;
        Bt = Bbase + (size_t)bh * 1048576 + (size_t)bx * 128 * 2048;
    } else {
        A  = Abase + (size_t)by * 128 * 4096 + (size_t)bz * (ktiles * 32);
        Bt = Bbase + (size_t)bx * 128 * 4096 + (size_t)bz * (ktiles * 32);
    }

    const int l  = tid & 63, w = tid >> 6;
    const int wm = (w >> 1) * 64, wn = (w & 1) * 64;         // wave tile origin
    const int lg = l >> 4, lr = l & 15;
    const int slot = (lg ^ ((lr >> 1) & 3)) << 4;            // swizzled 16B slot in 64B row

    f32x4 acc[4][4];
    #pragma unroll
    for (int m = 0; m < 4; ++m)
        #pragma unroll
        for (int n = 0; n < 4; ++n)
            #pragma unroll
            for (int r = 0; r < 4; ++r) acc[m][n][r] = 0.f;

    for (int t = 0; t < ktiles; ++t) {
        const int koff = t * 32;
        // ---- stage tile t (linear LDS dest, inverse-swizzled global source) ----
        #pragma unroll
        for (int i = 0; i < 2; ++i) {
            const int a   = (i * 256 + tid) * 16;            // linear byte in 8KB region
            const int row = a >> 6;                          // 0..127
            const int sp  = (a >> 4) & 3;                    // physical 16B slot
            const int cb  = (sp ^ ((row >> 1) & 3)) << 4;    // logical byte-in-row
            const u16* ga = A  + (size_t)row * LDA + koff + (cb >> 1);
            const u16* gb = Bt + (size_t)row * LDB + koff + (cb >> 1);
            lds_u32* la = (lds_u32*)((char*)&lsA[0][0] + i * 4096 + (w << 10));
            lds_u32* lb = (lds_u32*)((char*)&lsB[0][0] + i * 4096 + (w << 10));
            __builtin_amdgcn_global_load_lds((gbl_u32*)ga, la, 16, 0, 0);
            __builtin_amdgcn_global_load_lds((gbl_u32*)gb, lb, 16, 0, 0);
        }
        __syncthreads();                                     // drains vmcnt; tile resident

        // ---- compute: 16 MFMA (full BK=32 contraction) ----
        {
            s16x8 av[4], bv[4];
            #pragma unroll
            for (int m = 0; m < 4; ++m) {
                const int row = wm + m * 16 + lr;
                av[m] = *(const s16x8*)((const char*)&lsA[0][0] + row * 64 + slot);
            }
            #pragma unroll
            for (int n = 0; n < 4; ++n) {
                const int row = wn + n * 16 + lr;
                bv[n] = *(const s16x8*)((const char*)&lsB[0][0] + row * 64 + slot);
            }
            #pragma unroll
            for (int m = 0; m < 4; ++m)
                #pragma unroll
                for (int n = 0; n < 4; ++n)
                    acc[m][n] = __builtin_amdgcn_mfma_f32_16x16x32_bf16(av[m], bv[n], acc[m][n], 0, 0, 0);
        }
        __syncthreads();                                     // all reads done before next stage
    }

    // ---------------- epilogue: C/D col = lr, row = lg*4 + r  [m89 verified] ----------------
    if constexpr (MODE == 0) {
        const float* bias = (bz == 0) ? bias0 : ((bz == 1) ? bias1 : bias2);
        #pragma unroll
        for (int m = 0; m < 4; ++m)
        #pragma unroll
        for (int n = 0; n < 4; ++n)
        #pragma unroll
        for (int r = 0; r < 4; ++r) {
            const int grow = by * 128 + wm + m * 16 + lg * 4 + r;   // b*2048+s
            const int gcol = bx * 128 + wn + n * 16 + lr;           // h*512+d
            const u16 o = f2bf(acc[m][n][r] + bias[gcol]);
            const int bb = grow >> 11, ss = grow & 2047;
            const int hh = gcol >> 9,  dd = gcol & 511;
            if (bz == 0)      out0[(((size_t)(bb * 8 + hh) * 2048 + ss) << 9)  + dd] = o;
            else if (bz == 1) out1[(((size_t)(bb * 8 + hh) * 2048 + ss) << 9)  + dd] = o;
            else              out2[(((size_t)(bb * 8 + hh) * 512  + dd) << 11) + ss] = o; // v^T
        }
    } else if constexpr (MODE == 1) {
        const int bh = bh_base + bz;
        u16* Pp = out0 + (size_t)bz * 4194304;
        #pragma unroll
        for (int m = 0; m < 4; ++m)
        #pragma unroll
        for (int r = 0; r < 4; ++r) {
            const int grow = by * 128 + wm + m * 16 + lg * 4 + r;
            float rs = 0.f;
            #pragma unroll
            for (int n = 0; n < 4; ++n) {
                const int gcol = bx * 128 + wn + n * 16 + lr;
                float p = __expf(acc[m][n][r] * 0.04419417382415922f);  // 1/sqrt(512)
                rs += p;
                Pp[((size_t)grow << 11) + gcol] = f2bf(p);
            }
            #pragma unroll
            for (int o = 1; o < 16; o <<= 1) rs += __shfl_xor(rs, o, 64);
            if (lr == 0) atomicAdd(&rsum[bh * 2048 + grow], rs);
        }
    } else if constexpr (MODE == 2) {
        const int bh = bh_base + bz;
        const int bb = bh >> 3, hh = bh & 7;
        #pragma unroll
        for (int m = 0; m < 4; ++m)
        #pragma unroll
        for (int r = 0; r < 4; ++r) {
            const int grow = by * 128 + wm + m * 16 + lg * 4 + r;
            const float ri = 1.0f / rsum[bh * 2048 + grow];
            #pragma unroll
            for (int n = 0; n < 4; ++n) {
                const int gcol = bx * 128 + wn + n * 16 + lr;           // 0..511
                out0[((size_t)(bb * 2048 + grow) << 12) + hh * 512 + gcol] = f2bf(acc[m][n][r] * ri);
            }
        }
    } else {
        #pragma unroll
        for (int m = 0; m < 4; ++m)
        #pragma unroll
        for (int n = 0; n < 4; ++n)
        #pragma unroll
        for (int r = 0; r < 4; ++r) {
            const int grow = by * 128 + wm + m * 16 + lg * 4 + r;       // 0..4095
            const int gcol = bx * 128 + wn + n * 16 + lr;               // 0..511
            outf[(size_t)bz * 2097152 + (size_t)grow * 512 + gcol] = acc[m][n][r];
        }
    }
}

extern "C" void kernel_launch(void* const* d_in, const int* in_sizes, int n_in,
                              void* d_out, int out_size, void* d_ws, size_t ws_size,
                              hipStream_t stream) {
    const float* Q  = (const float*)d_in[0];
    const float* K  = (const float*)d_in[1];
    const float* V  = (const float*)d_in[2];
    const float* bq = (const float*)d_in[4];
    const float* bk = (const float*)d_in[6];
    const float* bv = (const float*)d_in[8];
    const float* bo = (const float*)d_in[10];
    const float* Wq = (const float*)d_in[3];
    const float* Wk = (const float*)d_in[5];
    const float* Wv = (const float*)d_in[7];
    const float* Wo = (const float*)d_in[9];
    float* out = (float*)d_out;

    char* ws = (char*)d_ws;
    u16*   qkvbf = (u16*)  (ws + 0);            // [3][4096][512] bf16
    u16*   Wt    = (u16*)  (ws + 12582912);     // Wq^T,Wk^T,Wv^T [3][4096][512]
    u16*   WoT   = (u16*)  (ws + 25165824);     // Wo^T [512][4096]
    float* rsum  = (float*)(ws + 29360128);     // [16][2048]
    u16*   qproj = (u16*)  (ws + 29491200);     // [B,H,S,512]
    u16*   kproj = (u16*)  (ws + 63045632);     // [B,H,S,512]
    u16*   vT    = (u16*)  (ws + 96600064);     // [B,H,512,S]
    u16*   Oattn = (u16*)  (ws + 130154496);    // [B*S][4096]
    u16*   P     = (u16*)  (ws + 163708928);    // chunked [ch][2048][2048]
    float* part  = (float*)(ws + 163708928);    // reused: [splitk][4096][512] f32

    size_t avail = (ws_size > (size_t)163708928) ? ws_size - (size_t)163708928 : 0;
    int hp = (int)(avail / 8388608);
    if (hp < 1)  hp = 1;
    if (hp > 16) hp = 16;
    int splitk = (hp >= 8) ? 8 : (hp >= 4) ? 4 : (hp >= 2) ? 2 : 1;

    // input converts
    k_cvt<<<2048, 256, 0, stream>>>(Q, qkvbf,            524288);
    k_cvt<<<2048, 256, 0, stream>>>(K, qkvbf + 2097152,  524288);
    k_cvt<<<2048, 256, 0, stream>>>(V, qkvbf + 4194304,  524288);
    dim3 tb(32, 8);
    k_tcvt<<<dim3(128, 16), tb, 0, stream>>>(Wq, Wt,            512, 4096);
    k_tcvt<<<dim3(128, 16), tb, 0, stream>>>(Wk, Wt + 2097152,  512, 4096);
    k_tcvt<<<dim3(128, 16), tb, 0, stream>>>(Wv, Wt + 4194304,  512, 4096);
    k_tcvt<<<dim3(16, 128), tb, 0, stream>>>(Wo, WoT,           4096, 512);
    k_zero<<<128, 256, 0, stream>>>(rsum, 32768);

    // fused QKV projections (+bias): q,k -> [B,H,S,D], v -> [B,H,D,S]
    k_gemm<0><<<dim3(32, 32, 3), 256, 0, stream>>>(qkvbf, Wt, qproj, kproj, vT, nullptr,
                                                   bq, bk, bv, nullptr, 0, 16);

    // attention: P = exp(qk^T*scale) with fused row-sums; O = P v / rowsum
    for (int h0 = 0; h0 < 16; h0 += hp) {
        int ch = (16 - h0 < hp) ? (16 - h0) : hp;
        k_gemm<1><<<dim3(16, 16, ch), 256, 0, stream>>>(qproj, kproj, P, nullptr, nullptr,
                                                        nullptr, nullptr, nullptr, nullptr,
                                                        rsum, h0, 16);
        k_gemm<2><<<dim3(4, 16, ch), 256, 0, stream>>>(P, vT, Oattn, nullptr, nullptr,
                                                       nullptr, nullptr, nullptr, nullptr,
                                                       rsum, h0, 64);
    }

    // final projection: split-K partials + reduce(+bias) -> f32 out
    k_gemm<3><<<dim3(4, 32, splitk), 256, 0, stream>>>(Oattn, WoT, nullptr, nullptr, nullptr,
                                                       part, nullptr, nullptr, nullptr,
                                                       nullptr, 0, 128 / splitk);
    k_reduce<<<2048, 256, 0, stream>>>(part, bo, out, splitk);
}

// Round 9
// 365.484 us; speedup vs baseline: 6.6251x; 6.6251x over previous
//
#include <hip/hip_runtime.h>
#include <cstdint>
#include <cstddef>

typedef unsigned int u32;
typedef unsigned short u16;
typedef float  f32x4 __attribute__((ext_vector_type(4)));
typedef short  s16x8 __attribute__((ext_vector_type(8)));
typedef unsigned short u16x4 __attribute__((ext_vector_type(4)));

typedef const __attribute__((address_space(1))) u32 gbl_u32;
typedef __attribute__((address_space(3))) u32 lds_u32;

__device__ __forceinline__ u16 f2bf(float f) {          // RNE f32->bf16 (finite inputs)
    u32 u = __builtin_bit_cast(u32, f);
    u = (u + 0x7FFFu + ((u >> 16) & 1u)) >> 16;
    return (u16)u;
}

// ---------------- fused elementwise f32 -> bf16 convert (Q,K,V in one launch) ------------
__global__ void k_cvt3(const float* __restrict__ s0, const float* __restrict__ s1,
                       const float* __restrict__ s2, u16* __restrict__ d) {
    int i = blockIdx.x * 256 + threadIdx.x;              // float4 id, 3*524288 total
    int seg = i >> 19, off = i & 524287;
    const float* s = (seg == 0) ? s0 : (seg == 1) ? s1 : s2;
    float4 v = ((const float4*)s)[off];
    u16x4 o = { f2bf(v.x), f2bf(v.y), f2bf(v.z), f2bf(v.w) };
    *(u16x4*)(d + (size_t)i * 4) = o;
}

// ------- batched transpose+convert: W[bz] f32 [R][C] -> bf16 [C][R] (R=512, C=4096) ------
__global__ void k_tcvt3(const float* __restrict__ s0, const float* __restrict__ s1,
                        const float* __restrict__ s2, u16* __restrict__ d) {
    __shared__ float t[32][33];
    const int R = 512, C = 4096;
    int bx = blockIdx.x, by = blockIdx.y, bz = blockIdx.z;
    const float* s = (bz == 0) ? s0 : (bz == 1) ? s1 : s2;
    u16* dd = d + (size_t)bz * 2097152;
    int tx = threadIdx.x, ty = threadIdx.y;
    #pragma unroll
    for (int j = ty; j < 32; j += 8)
        t[j][tx] = s[(size_t)(by * 32 + j) * C + bx * 32 + tx];
    __syncthreads();
    #pragma unroll
    for (int j = ty; j < 32; j += 8)
        dd[(size_t)(bx * 32 + j) * R + by * 32 + tx] = f2bf(t[tx][j]);
}

// ---------------- transpose + convert: src f32 [R][C] -> dst bf16 [C][R] ----------------
__global__ void k_tcvt(const float* __restrict__ s, u16* __restrict__ d, int R, int C) {
    __shared__ float t[32][33];
    int bx = blockIdx.x, by = blockIdx.y;
    int tx = threadIdx.x, ty = threadIdx.y;
    #pragma unroll
    for (int j = ty; j < 32; j += 8)
        t[j][tx] = s[(size_t)(by * 32 + j) * C + bx * 32 + tx];
    __syncthreads();
    #pragma unroll
    for (int j = ty; j < 32; j += 8)
        d[(size_t)(bx * 32 + j) * R + by * 32 + tx] = f2bf(t[tx][j]);
}

__global__ void k_zero(float* __restrict__ p, int n) {
    int i = blockIdx.x * 256 + threadIdx.x;
    if (i < n) p[i] = 0.f;
}

// final reduce: out = bias + sum over splitk partials   (2097152 f32 = 524288 float4)
__global__ void k_reduce(const float* __restrict__ part, const float* __restrict__ bias,
                         float* __restrict__ out, int splitk) {
    int i = blockIdx.x * 256 + threadIdx.x;          // float4 id
    float4 s = ((const float4*)bias)[i & 127];
    for (int j = 0; j < splitk; ++j) {
        float4 p = ((const float4*)part)[(size_t)j * 524288 + i];
        s.x += p.x; s.y += p.y; s.z += p.z; s.w += p.w;
    }
    ((float4*)out)[i] = s;
}

// ================= 128x128xK bf16 GEMM, B given transposed [N][K] ==================
// m97-structure: 4 waves (2x2), BK=64, single-buffered 32 KiB LDS, plain
// __syncthreads 2-barrier loop; 4 blocks/CU (launch_bounds(256,4): 60 VGPR + 64 AGPR
// = 124 <= 128 -- spill-free max occupancy). XCD-bijective block swizzle (m204) on a
// flat 1-D grid. XOR-swizzled LDS (0-conflict verified), global_load_lds width 16.
// MODE 0: QKV projections (z=mat)   MODE 1: P=exp(qk^T*scale)+rowsum-atomic
// MODE 2: O=(P v)/rowsum            MODE 3: split-K partials of Oattn@Wo
template<int MODE>
__global__ __launch_bounds__(256, 4) void k_gemm(
    const u16* __restrict__ Abase, const u16* __restrict__ Bbase,
    u16* __restrict__ out0, u16* __restrict__ out1, u16* __restrict__ out2,
    float* __restrict__ outf,
    const float* __restrict__ bias0, const float* __restrict__ bias1,
    const float* __restrict__ bias2,
    float* __restrict__ rsum, int bh_base, int ktiles, int nx, int ny)
{
    constexpr int LDA = (MODE == 2) ? 2048 : (MODE == 3) ? 4096 : 512;
    constexpr int LDB = (MODE == 2) ? 2048 : (MODE == 3) ? 4096 : 512;

    __shared__ u16 lsA[128][64];       // 16 KiB
    __shared__ u16 lsB[128][64];       // 16 KiB

    const int tid = threadIdx.x;

    // XCD-bijective swizzle: total % 8 == 0 always (grids are multiples of 64)
    const int total = gridDim.x;
    const int q8 = total >> 3;
    const int flat = blockIdx.x;
    const int swzid = (flat & 7) * q8 + (flat >> 3);
    const int nxy = nx * ny;
    const int bz = swzid / nxy;
    const int rem = swzid - bz * nxy;
    const int by = rem / nx;
    const int bx = rem - by * nx;

    const u16* A; const u16* Bt;
    if constexpr (MODE == 0) {
        A  = Abase + (size_t)bz * 2097152 + (size_t)by * 128 * 512;
        Bt = Bbase + (size_t)bz * 2097152 + (size_t)bx * 128 * 512;
    } else if constexpr (MODE == 1) {
        int bh = bh_base + bz;
        A  = Abase + (size_t)bh * 1048576 + (size_t)by * 128 * 512;
        Bt = Bbase + (size_t)bh * 1048576 + (size_t)bx * 128 * 512;
    } else if constexpr (MODE == 2) {
        int bh = bh_base + bz;
        A  = Abase + (size_t)bz * 4194304 + (size_t)by * 128 * 2048;
        Bt = Bbase + (size_t)bh * 1048576 + (size_t)bx * 128 * 2048;
    } else {
        A  = Abase + (size_t)by * 128 * 4096 + (size_t)bz * (ktiles * 64);
        Bt = Bbase + (size_t)bx * 128 * 4096 + (size_t)bz * (ktiles * 64);
    }

    const int l  = tid & 63, w = tid >> 6;
    const int wm = (w >> 1) * 64, wn = (w & 1) * 64;         // wave tile origin
    const int lg = l >> 4, lr = l & 15;
    const int swz = (lr & 7) << 4;

    f32x4 acc[4][4];
    #pragma unroll
    for (int m = 0; m < 4; ++m)
        #pragma unroll
        for (int n = 0; n < 4; ++n)
            #pragma unroll
            for (int r = 0; r < 4; ++r) acc[m][n][r] = 0.f;

    for (int t = 0; t < ktiles; ++t) {
        const int koff = t * 64;
        // ---- stage tile t (linear LDS dest, inverse-swizzled global source) ----
        #pragma unroll
        for (int i = 0; i < 4; ++i) {
            const int a   = (i * 256 + tid) * 16;            // linear byte in 16KB region
            const int row = a >> 7;                          // 0..127
            const int cb  = (a & 127) ^ ((row & 7) << 4);    // logical byte-in-row
            const u16* ga = A  + (size_t)row * LDA + koff + (cb >> 1);
            const u16* gb = Bt + (size_t)row * LDB + koff + (cb >> 1);
            lds_u32* la = (lds_u32*)((char*)&lsA[0][0] + i * 4096 + (w << 10));
            lds_u32* lb = (lds_u32*)((char*)&lsB[0][0] + i * 4096 + (w << 10));
            __builtin_amdgcn_global_load_lds((gbl_u32*)ga, la, 16, 0, 0);
            __builtin_amdgcn_global_load_lds((gbl_u32*)gb, lb, 16, 0, 0);
        }
        __syncthreads();                                     // drains vmcnt; tile resident

        // ---- compute: 2 k-slices x 16 MFMA ----
        #pragma unroll
        for (int ks = 0; ks < 2; ++ks) {
            s16x8 av[4], bv[4];
            #pragma unroll
            for (int m = 0; m < 4; ++m) {
                const int row = wm + m * 16 + lr;
                av[m] = *(const s16x8*)((const char*)&lsA[0][0] + row * 128 + ((ks * 64 + lg * 16) ^ swz));
            }
            #pragma unroll
            for (int n = 0; n < 4; ++n) {
                const int row = wn + n * 16 + lr;
                bv[n] = *(const s16x8*)((const char*)&lsB[0][0] + row * 128 + ((ks * 64 + lg * 16) ^ swz));
            }
            #pragma unroll
            for (int m = 0; m < 4; ++m)
                #pragma unroll
                for (int n = 0; n < 4; ++n)
                    acc[m][n] = __builtin_amdgcn_mfma_f32_16x16x32_bf16(av[m], bv[n], acc[m][n], 0, 0, 0);
        }
        __syncthreads();                                     // all reads done before next stage
    }

    // ---------------- epilogue: C/D col = lr, row = lg*4 + r  [m89 verified] ----------------
    if constexpr (MODE == 0) {
        const float* bias = (bz == 0) ? bias0 : ((bz == 1) ? bias1 : bias2);
        #pragma unroll
        for (int m = 0; m < 4; ++m)
        #pragma unroll
        for (int n = 0; n < 4; ++n)
        #pragma unroll
        for (int r = 0; r < 4; ++r) {
            const int grow = by * 128 + wm + m * 16 + lg * 4 + r;   // b*2048+s
            const int gcol = bx * 128 + wn + n * 16 + lr;           // h*512+d
            const u16 o = f2bf(acc[m][n][r] + bias[gcol]);
            const int bb = grow >> 11, ss = grow & 2047;
            const int hh = gcol >> 9,  dd = gcol & 511;
            if (bz == 0)      out0[(((size_t)(bb * 8 + hh) * 2048 + ss) << 9)  + dd] = o;
            else if (bz == 1) out1[(((size_t)(bb * 8 + hh) * 2048 + ss) << 9)  + dd] = o;
            else              out2[(((size_t)(bb * 8 + hh) * 512  + dd) << 11) + ss] = o; // v^T
        }
    } else if constexpr (MODE == 1) {
        const int bh = bh_base + bz;
        u16* Pp = out0 + (size_t)bz * 4194304;
        #pragma unroll
        for (int m = 0; m < 4; ++m)
        #pragma unroll
        for (int r = 0; r < 4; ++r) {
            const int grow = by * 128 + wm + m * 16 + lg * 4 + r;
            float rs = 0.f;
            #pragma unroll
            for (int n = 0; n < 4; ++n) {
                const int gcol = bx * 128 + wn + n * 16 + lr;
                float p = __expf(acc[m][n][r] * 0.04419417382415922f);  // 1/sqrt(512)
                rs += p;
                Pp[((size_t)grow << 11) + gcol] = f2bf(p);
            }
            #pragma unroll
            for (int o = 1; o < 16; o <<= 1) rs += __shfl_xor(rs, o, 64);
            if (lr == 0) atomicAdd(&rsum[bh * 2048 + grow], rs);
        }
    } else if constexpr (MODE == 2) {
        const int bh = bh_base + bz;
        const int bb = bh >> 3, hh = bh & 7;
        #pragma unroll
        for (int m = 0; m < 4; ++m)
        #pragma unroll
        for (int r = 0; r < 4; ++r) {
            const int grow = by * 128 + wm + m * 16 + lg * 4 + r;
            const float ri = 1.0f / rsum[bh * 2048 + grow];
            #pragma unroll
            for (int n = 0; n < 4; ++n) {
                const int gcol = bx * 128 + wn + n * 16 + lr;           // 0..511
                out0[((size_t)(bb * 2048 + grow) << 12) + hh * 512 + gcol] = f2bf(acc[m][n][r] * ri);
            }
        }
    } else {
        #pragma unroll
        for (int m = 0; m < 4; ++m)
        #pragma unroll
        for (int n = 0; n < 4; ++n)
        #pragma unroll
        for (int r = 0; r < 4; ++r) {
            const int grow = by * 128 + wm + m * 16 + lg * 4 + r;       // 0..4095
            const int gcol = bx * 128 + wn + n * 16 + lr;               // 0..511
            outf[(size_t)bz * 2097152 + (size_t)grow * 512 + gcol] = acc[m][n][r];
        }
    }
}

extern "C" void kernel_launch(void* const* d_in, const int* in_sizes, int n_in,
                              void* d_out, int out_size, void* d_ws, size_t ws_size,
                              hipStream_t stream) {
    const float* Q  = (const float*)d_in[0];
    const float* K  = (const float*)d_in[1];
    const float* V  = (const float*)d_in[2];
    const float* bq = (const float*)d_in[4];
    const float* bk = (const float*)d_in[6];
    const float* bv = (const float*)d_in[8];
    const float* bo = (const float*)d_in[10];
    const float* Wq = (const float*)d_in[3];
    const float* Wk = (const float*)d_in[5];
    const float* Wv = (const float*)d_in[7];
    const float* Wo = (const float*)d_in[9];
    float* out = (float*)d_out;

    char* ws = (char*)d_ws;
    u16*   qkvbf = (u16*)  (ws + 0);            // [3][4096][512] bf16
    u16*   Wt    = (u16*)  (ws + 12582912);     // Wq^T,Wk^T,Wv^T [3][4096][512]
    u16*   WoT   = (u16*)  (ws + 25165824);     // Wo^T [512][4096]
    float* rsum  = (float*)(ws + 29360128);     // [16][2048]
    u16*   qproj = (u16*)  (ws + 29491200);     // [B,H,S,512]
    u16*   kproj = (u16*)  (ws + 63045632);     // [B,H,S,512]
    u16*   vT    = (u16*)  (ws + 96600064);     // [B,H,512,S]
    u16*   Oattn = (u16*)  (ws + 130154496);    // [B*S][4096]
    u16*   P     = (u16*)  (ws + 163708928);    // chunked [ch][2048][2048]
    float* part  = (float*)(ws + 163708928);    // reused: [splitk][4096][512] f32

    size_t avail = (ws_size > (size_t)163708928) ? ws_size - (size_t)163708928 : 0;
    int hp = (int)(avail / 8388608);
    if (hp < 1)  hp = 1;
    if (hp > 16) hp = 16;
    int splitk = (hp >= 8) ? 8 : (hp >= 4) ? 4 : (hp >= 2) ? 2 : 1;

    // input converts (fused launches)
    k_cvt3<<<6144, 256, 0, stream>>>(Q, K, V, qkvbf);
    dim3 tb(32, 8);
    k_tcvt3<<<dim3(128, 16, 3), tb, 0, stream>>>(Wq, Wk, Wv, Wt);
    k_tcvt<<<dim3(16, 128), tb, 0, stream>>>(Wo, WoT, 4096, 512);
    k_zero<<<128, 256, 0, stream>>>(rsum, 32768);

    // fused QKV projections (+bias): q,k -> [B,H,S,D], v -> [B,H,D,S]
    k_gemm<0><<<32 * 32 * 3, 256, 0, stream>>>(qkvbf, Wt, qproj, kproj, vT, nullptr,
                                               bq, bk, bv, nullptr, 0, 8, 32, 32);

    // attention: P = exp(qk^T*scale) with fused row-sums; O = P v / rowsum
    for (int h0 = 0; h0 < 16; h0 += hp) {
        int ch = (16 - h0 < hp) ? (16 - h0) : hp;
        k_gemm<1><<<16 * 16 * ch, 256, 0, stream>>>(qproj, kproj, P, nullptr, nullptr,
                                                    nullptr, nullptr, nullptr, nullptr,
                                                    rsum, h0, 8, 16, 16);
        k_gemm<2><<<4 * 16 * ch, 256, 0, stream>>>(P, vT, Oattn, nullptr, nullptr,
                                                   nullptr, nullptr, nullptr, nullptr,
                                                   rsum, h0, 32, 4, 16);
    }

    // final projection: split-K partials + reduce(+bias) -> f32 out
    k_gemm<3><<<4 * 32 * splitk, 256, 0, stream>>>(Oattn, WoT, nullptr, nullptr, nullptr,
                                                   part, nullptr, nullptr, nullptr,
                                                   nullptr, 0, 64 / splitk, 4, 32);
    k_reduce<<<2048, 256, 0, stream>>>(part, bo, out, splitk);
}

// Round 10
// 362.234 us; speedup vs baseline: 6.6845x; 1.0090x over previous
//
#include <hip/hip_runtime.h>
#include <cstdint>
#include <cstddef>

typedef unsigned int u32;
typedef unsigned short u16;
typedef float  f32x4 __attribute__((ext_vector_type(4)));
typedef short  s16x8 __attribute__((ext_vector_type(8)));
typedef unsigned short u16x4 __attribute__((ext_vector_type(4)));

typedef const __attribute__((address_space(1))) u32 gbl_u32;
typedef __attribute__((address_space(3))) u32 lds_u32;

__device__ __forceinline__ u16 f2bf(float f) {          // RNE f32->bf16 (finite inputs)
    u32 u = __builtin_bit_cast(u32, f);
    u = (u + 0x7FFFu + ((u >> 16) & 1u)) >> 16;
    return (u16)u;
}

// ---------------- fused elementwise f32 -> bf16 convert (Q,K,V in one launch) ------------
__global__ void k_cvt3(const float* __restrict__ s0, const float* __restrict__ s1,
                       const float* __restrict__ s2, u16* __restrict__ d) {
    int i = blockIdx.x * 256 + threadIdx.x;              // float4 id, 3*524288 total
    int seg = i >> 19, off = i & 524287;
    const float* s = (seg == 0) ? s0 : (seg == 1) ? s1 : s2;
    float4 v = ((const float4*)s)[off];
    u16x4 o = { f2bf(v.x), f2bf(v.y), f2bf(v.z), f2bf(v.w) };
    *(u16x4*)(d + (size_t)i * 4) = o;
}

// ------- batched transpose+convert: W[bz] f32 [R][C] -> bf16 [C][R] (R=512, C=4096) ------
__global__ void k_tcvt3(const float* __restrict__ s0, const float* __restrict__ s1,
                        const float* __restrict__ s2, u16* __restrict__ d) {
    __shared__ float t[32][33];
    const int R = 512, C = 4096;
    int bx = blockIdx.x, by = blockIdx.y, bz = blockIdx.z;
    const float* s = (bz == 0) ? s0 : (bz == 1) ? s1 : s2;
    u16* dd = d + (size_t)bz * 2097152;
    int tx = threadIdx.x, ty = threadIdx.y;
    #pragma unroll
    for (int j = ty; j < 32; j += 8)
        t[j][tx] = s[(size_t)(by * 32 + j) * C + bx * 32 + tx];
    __syncthreads();
    #pragma unroll
    for (int j = ty; j < 32; j += 8)
        dd[(size_t)(bx * 32 + j) * R + by * 32 + tx] = f2bf(t[tx][j]);
}

// ---------------- transpose + convert: src f32 [R][C] -> dst bf16 [C][R] ----------------
__global__ void k_tcvt(const float* __restrict__ s, u16* __restrict__ d, int R, int C) {
    __shared__ float t[32][33];
    int bx = blockIdx.x, by = blockIdx.y;
    int tx = threadIdx.x, ty = threadIdx.y;
    #pragma unroll
    for (int j = ty; j < 32; j += 8)
        t[j][tx] = s[(size_t)(by * 32 + j) * C + bx * 32 + tx];
    __syncthreads();
    #pragma unroll
    for (int j = ty; j < 32; j += 8)
        d[(size_t)(bx * 32 + j) * R + by * 32 + tx] = f2bf(t[tx][j]);
}

__global__ void k_zero(float* __restrict__ p, int n) {
    int i = blockIdx.x * 256 + threadIdx.x;
    if (i < n) p[i] = 0.f;
}

// final reduce: out = bias + sum over splitk partials   (2097152 f32 = 524288 float4)
__global__ void k_reduce(const float* __restrict__ part, const float* __restrict__ bias,
                         float* __restrict__ out, int splitk) {
    int i = blockIdx.x * 256 + threadIdx.x;          // float4 id
    float4 s = ((const float4*)bias)[i & 127];
    for (int j = 0; j < splitk; ++j) {
        float4 p = ((const float4*)part)[(size_t)j * 524288 + i];
        s.x += p.x; s.y += p.y; s.z += p.z; s.w += p.w;
    }
    ((float4*)out)[i] = s;
}

// ================= 256x128xK bf16 GEMM, B given transposed [N][K] ==================
// L2-traffic-optimized m97-style: 8 waves (4M x 2N), BK=64, SINGLE-buffered 48 KiB
// LDS, plain __syncthreads 2-barrier loop; 2 blocks/CU (regs: 60 VGPR + 64 AGPR =
// 124 <= 128 at 4 waves/SIMD). 256x128 tile halves staged L2 bytes vs 128x128.
// XOR-swizzled LDS (0-conflict verified), global_load_lds width 16. No blockIdx swizzle.
// MODE 0: QKV projections (bz=mat)  MODE 1: P=exp(qk^T*scale)+rowsum-atomic
// MODE 2: O=(P v)/rowsum            MODE 3: split-K partials of Oattn@Wo
template<int MODE>
__global__ __launch_bounds__(512, 4) void k_gemm(
    const u16* __restrict__ Abase, const u16* __restrict__ Bbase,
    u16* __restrict__ out0, u16* __restrict__ out1, u16* __restrict__ out2,
    float* __restrict__ outf,
    const float* __restrict__ bias0, const float* __restrict__ bias1,
    const float* __restrict__ bias2,
    float* __restrict__ rsum, int bh_base, int ktiles)
{
    constexpr int LDA = (MODE == 2) ? 2048 : (MODE == 3) ? 4096 : 512;
    constexpr int LDB = (MODE == 2) ? 2048 : (MODE == 3) ? 4096 : 512;

    __shared__ u16 lsA[256][64];       // 32 KiB
    __shared__ u16 lsB[128][64];       // 16 KiB

    const int tid = threadIdx.x;
    const int bx = blockIdx.x, by = blockIdx.y, bz = blockIdx.z;

    const u16* A; const u16* Bt;
    if constexpr (MODE == 0) {
        A  = Abase + (size_t)bz * 2097152 + (size_t)by * 256 * 512;
        Bt = Bbase + (size_t)bz * 2097152 + (size_t)bx * 128 * 512;
    } else if constexpr (MODE == 1) {
        int bh = bh_base + bz;
        A  = Abase + (size_t)bh * 1048576 + (size_t)by * 256 * 512;
        Bt = Bbase + (size_t)bh * 1048576 + (size_t)bx * 128 * 512;
    } else if constexpr (MODE == 2) {
        int bh = bh_base + bz;
        A  = Abase + (size_t)bz * 4194304 + (size_t)by * 256 * 2048;
        Bt = Bbase + (size_t)bh * 1048576 + (size_t)bx * 128 * 2048;
    } else {
        A  = Abase + (size_t)by * 256 * 4096 + (size_t)bz * (ktiles * 64);
        Bt = Bbase + (size_t)bx * 128 * 4096 + (size_t)bz * (ktiles * 64);
    }

    const int l  = tid & 63, w = tid >> 6;
    const int wm = (w >> 1) * 64, wn = (w & 1) * 64;         // 4 M-waves x 2 N-waves
    const int lg = l >> 4, lr = l & 15;
    const int swz = (lr & 7) << 4;

    f32x4 acc[4][4];
    #pragma unroll
    for (int m = 0; m < 4; ++m)
        #pragma unroll
        for (int n = 0; n < 4; ++n)
            #pragma unroll
            for (int r = 0; r < 4; ++r) acc[m][n][r] = 0.f;

    for (int t = 0; t < ktiles; ++t) {
        const int koff = t * 64;
        // ---- stage tile t: A 32 KB (4 rounds), B 16 KB (2 rounds); linear LDS dest,
        //      inverse-swizzled global source ----
        #pragma unroll
        for (int i = 0; i < 4; ++i) {
            const int a   = (i * 512 + tid) * 16;            // linear byte in 32KB region
            const int row = a >> 7;                          // 0..255
            const int cb  = (a & 127) ^ ((row & 7) << 4);    // logical byte-in-row
            const u16* ga = A + (size_t)row * LDA + koff + (cb >> 1);
            lds_u32* la = (lds_u32*)((char*)&lsA[0][0] + i * 8192 + (w << 10));
            __builtin_amdgcn_global_load_lds((gbl_u32*)ga, la, 16, 0, 0);
        }
        #pragma unroll
        for (int i = 0; i < 2; ++i) {
            const int a   = (i * 512 + tid) * 16;            // linear byte in 16KB region
            const int row = a >> 7;                          // 0..127
            const int cb  = (a & 127) ^ ((row & 7) << 4);
            const u16* gb = Bt + (size_t)row * LDB + koff + (cb >> 1);
            lds_u32* lb = (lds_u32*)((char*)&lsB[0][0] + i * 8192 + (w << 10));
            __builtin_amdgcn_global_load_lds((gbl_u32*)gb, lb, 16, 0, 0);
        }
        __syncthreads();                                     // drains vmcnt; tile resident

        // ---- compute: 2 k-slices x 16 MFMA ----
        #pragma unroll
        for (int ks = 0; ks < 2; ++ks) {
            s16x8 av[4], bv[4];
            #pragma unroll
            for (int m = 0; m < 4; ++m) {
                const int row = wm + m * 16 + lr;
                av[m] = *(const s16x8*)((const char*)&lsA[0][0] + row * 128 + ((ks * 64 + lg * 16) ^ swz));
            }
            #pragma unroll
            for (int n = 0; n < 4; ++n) {
                const int row = wn + n * 16 + lr;
                bv[n] = *(const s16x8*)((const char*)&lsB[0][0] + row * 128 + ((ks * 64 + lg * 16) ^ swz));
            }
            #pragma unroll
            for (int m = 0; m < 4; ++m)
                #pragma unroll
                for (int n = 0; n < 4; ++n)
                    acc[m][n] = __builtin_amdgcn_mfma_f32_16x16x32_bf16(av[m], bv[n], acc[m][n], 0, 0, 0);
        }
        __syncthreads();                                     // all reads done before next stage
    }

    // ---------------- epilogue: C/D col = lr, row = lg*4 + r  [m89 verified] ----------------
    if constexpr (MODE == 0) {
        const float* bias = (bz == 0) ? bias0 : ((bz == 1) ? bias1 : bias2);
        #pragma unroll
        for (int m = 0; m < 4; ++m)
        #pragma unroll
        for (int n = 0; n < 4; ++n)
        #pragma unroll
        for (int r = 0; r < 4; ++r) {
            const int grow = by * 256 + wm + m * 16 + lg * 4 + r;   // b*2048+s
            const int gcol = bx * 128 + wn + n * 16 + lr;           // h*512+d
            const u16 o = f2bf(acc[m][n][r] + bias[gcol]);
            const int bb = grow >> 11, ss = grow & 2047;
            const int hh = gcol >> 9,  dd = gcol & 511;
            if (bz == 0)      out0[(((size_t)(bb * 8 + hh) * 2048 + ss) << 9)  + dd] = o;
            else if (bz == 1) out1[(((size_t)(bb * 8 + hh) * 2048 + ss) << 9)  + dd] = o;
            else              out2[(((size_t)(bb * 8 + hh) * 512  + dd) << 11) + ss] = o; // v^T
        }
    } else if constexpr (MODE == 1) {
        const int bh = bh_base + bz;
        u16* Pp = out0 + (size_t)bz * 4194304;
        #pragma unroll
        for (int m = 0; m < 4; ++m)
        #pragma unroll
        for (int r = 0; r < 4; ++r) {
            const int grow = by * 256 + wm + m * 16 + lg * 4 + r;
            float rs = 0.f;
            #pragma unroll
            for (int n = 0; n < 4; ++n) {
                const int gcol = bx * 128 + wn + n * 16 + lr;
                float p = __expf(acc[m][n][r] * 0.04419417382415922f);  // 1/sqrt(512)
                rs += p;
                Pp[((size_t)grow << 11) + gcol] = f2bf(p);
            }
            #pragma unroll
            for (int o = 1; o < 16; o <<= 1) rs += __shfl_xor(rs, o, 64);
            if (lr == 0) atomicAdd(&rsum[bh * 2048 + grow], rs);
        }
    } else if constexpr (MODE == 2) {
        const int bh = bh_base + bz;
        const int bb = bh >> 3, hh = bh & 7;
        #pragma unroll
        for (int m = 0; m < 4; ++m)
        #pragma unroll
        for (int r = 0; r < 4; ++r) {
            const int grow = by * 256 + wm + m * 16 + lg * 4 + r;
            const float ri = 1.0f / rsum[bh * 2048 + grow];
            #pragma unroll
            for (int n = 0; n < 4; ++n) {
                const int gcol = bx * 128 + wn + n * 16 + lr;           // 0..511
                out0[((size_t)(bb * 2048 + grow) << 12) + hh * 512 + gcol] = f2bf(acc[m][n][r] * ri);
            }
        }
    } else {
        #pragma unroll
        for (int m = 0; m < 4; ++m)
        #pragma unroll
        for (int n = 0; n < 4; ++n)
        #pragma unroll
        for (int r = 0; r < 4; ++r) {
            const int grow = by * 256 + wm + m * 16 + lg * 4 + r;       // 0..4095
            const int gcol = bx * 128 + wn + n * 16 + lr;               // 0..511
            outf[(size_t)bz * 2097152 + (size_t)grow * 512 + gcol] = acc[m][n][r];
        }
    }
}

extern "C" void kernel_launch(void* const* d_in, const int* in_sizes, int n_in,
                              void* d_out, int out_size, void* d_ws, size_t ws_size,
                              hipStream_t stream) {
    const float* Q  = (const float*)d_in[0];
    const float* K  = (const float*)d_in[1];
    const float* V  = (const float*)d_in[2];
    const float* bq = (const float*)d_in[4];
    const float* bk = (const float*)d_in[6];
    const float* bv = (const float*)d_in[8];
    const float* bo = (const float*)d_in[10];
    const float* Wq = (const float*)d_in[3];
    const float* Wk = (const float*)d_in[5];
    const float* Wv = (const float*)d_in[7];
    const float* Wo = (const float*)d_in[9];
    float* out = (float*)d_out;

    char* ws = (char*)d_ws;
    u16*   qkvbf = (u16*)  (ws + 0);            // [3][4096][512] bf16
    u16*   Wt    = (u16*)  (ws + 12582912);     // Wq^T,Wk^T,Wv^T [3][4096][512]
    u16*   WoT   = (u16*)  (ws + 25165824);     // Wo^T [512][4096]
    float* rsum  = (float*)(ws + 29360128);     // [16][2048]
    u16*   qproj = (u16*)  (ws + 29491200);     // [B,H,S,512]
    u16*   kproj = (u16*)  (ws + 63045632);     // [B,H,S,512]
    u16*   vT    = (u16*)  (ws + 96600064);     // [B,H,512,S]
    u16*   Oattn = (u16*)  (ws + 130154496);    // [B*S][4096]
    u16*   P     = (u16*)  (ws + 163708928);    // chunked [ch][2048][2048]
    float* part  = (float*)(ws + 163708928);    // reused: [splitk][4096][512] f32

    size_t avail = (ws_size > (size_t)163708928) ? ws_size - (size_t)163708928 : 0;
    int hp = (int)(avail / 8388608);
    if (hp < 1)  hp = 1;
    if (hp > 16) hp = 16;
    int splitk = (hp >= 8) ? 8 : (hp >= 4) ? 4 : (hp >= 2) ? 2 : 1;

    // input converts (fused launches)
    k_cvt3<<<6144, 256, 0, stream>>>(Q, K, V, qkvbf);
    dim3 tb(32, 8);
    k_tcvt3<<<dim3(128, 16, 3), tb, 0, stream>>>(Wq, Wk, Wv, Wt);
    k_tcvt<<<dim3(16, 128), tb, 0, stream>>>(Wo, WoT, 4096, 512);
    k_zero<<<128, 256, 0, stream>>>(rsum, 32768);

    // fused QKV projections (+bias): q,k -> [B,H,S,D], v -> [B,H,D,S]
    k_gemm<0><<<dim3(32, 16, 3), 512, 0, stream>>>(qkvbf, Wt, qproj, kproj, vT, nullptr,
                                                   bq, bk, bv, nullptr, 0, 8);

    // attention: P = exp(qk^T*scale) with fused row-sums; O = P v / rowsum
    for (int h0 = 0; h0 < 16; h0 += hp) {
        int ch = (16 - h0 < hp) ? (16 - h0) : hp;
        k_gemm<1><<<dim3(16, 8, ch), 512, 0, stream>>>(qproj, kproj, P, nullptr, nullptr,
                                                       nullptr, nullptr, nullptr, nullptr,
                                                       rsum, h0, 8);
        k_gemm<2><<<dim3(4, 8, ch), 512, 0, stream>>>(P, vT, Oattn, nullptr, nullptr,
                                                      nullptr, nullptr, nullptr, nullptr,
                                                      rsum, h0, 32);
    }

    // final projection: split-K partials + reduce(+bias) -> f32 out
    k_gemm<3><<<dim3(4, 16, splitk), 512, 0, stream>>>(Oattn, WoT, nullptr, nullptr, nullptr,
                                                       part, nullptr, nullptr, nullptr,
                                                       nullptr, 0, 64 / splitk);
    k_reduce<<<2048, 256, 0, stream>>>(part, bo, out, splitk);
}